// Round 6
// baseline (293.665 us; speedup 1.0000x reference)
//
#include <hip/hip_runtime.h>

#define Bn 4
#define Sn 2048
#define Dn 1024

typedef short bf16x8 __attribute__((ext_vector_type(8)));
typedef float f32x4 __attribute__((ext_vector_type(4)));

__device__ __forceinline__ unsigned f2bf(float x) {
    unsigned u = __float_as_uint(x);
    return (u + 0x7FFFu + ((u >> 16) & 1u)) >> 16;
}

__device__ __forceinline__ uint2 pack4(float4 v) {
    uint2 p;
    p.x = f2bf(v.x) | (f2bf(v.y) << 16);
    p.y = f2bf(v.z) | (f2bf(v.w) << 16);
    return p;
}

__device__ __forceinline__ float bf2f(unsigned short s) {
    return __uint_as_float((unsigned)s << 16);
}

__device__ __forceinline__ void gl_lds16(const unsigned short* g, unsigned short* l) {
    __builtin_amdgcn_global_load_lds(
        (const __attribute__((address_space(1))) unsigned int*)g,
        (__attribute__((address_space(3))) unsigned int*)l, 16, 0, 0);
}

// ---------------------------------------------------------------------------
// Prep (fused): blocks [0,8192) copy-convert Q,K fp32->bf16;
// blocks [8192,9216) transpose V fp32 [B][S][D] -> Vt bf16 [B][D][S].
// ---------------------------------------------------------------------------
__global__ __launch_bounds__(256) void prep_kernel(
    const float* __restrict__ Q, const float* __restrict__ K,
    const float* __restrict__ V,
    unsigned short* __restrict__ Q16, unsigned short* __restrict__ K16,
    unsigned short* __restrict__ Vt) {
    __shared__ unsigned short Ts[128 * 66];
    const int bid = blockIdx.x;
    const int t = threadIdx.x;
    if (bid < 8192) {
        size_t i = (size_t)bid * 256 + t;
        float4 q = ((const float4*)Q)[i];
        ((uint2*)Q16)[i] = pack4(q);
        float4 k = ((const float4*)K)[i];
        ((uint2*)K16)[i] = pack4(k);
        return;
    }
    const int tb = bid - 8192;  // 1024 transpose tiles
    const int s0 = (tb & 15) * 128, d0 = ((tb >> 4) & 15) * 64, b = tb >> 8;
    const float* Vb = V + ((size_t)b * Sn + s0) * Dn + d0;
#pragma unroll
    for (int i = 0; i < 8; i++) {
        int task = i * 256 + t;
        int r = task >> 4, c4 = task & 15;
        float4 v = *(const float4*)(Vb + (size_t)r * Dn + c4 * 4);
        *(uint2*)(&Ts[r * 66 + c4 * 4]) = pack4(v);
    }
    __syncthreads();
    unsigned short* Vtb = Vt + ((size_t)b * Dn + d0) * Sn + s0;
#pragma unroll
    for (int i = 0; i < 4; i++) {
        int task = i * 256 + t;
        int sc = task & 15, dr = task >> 4;
        unsigned short tmp[8];
#pragma unroll
        for (int j = 0; j < 8; j++) tmp[j] = Ts[(sc * 8 + j) * 66 + dr];
        uint4 u;
        u.x = tmp[0] | ((unsigned)tmp[1] << 16);
        u.y = tmp[2] | ((unsigned)tmp[3] << 16);
        u.z = tmp[4] | ((unsigned)tmp[5] << 16);
        u.w = tmp[6] | ((unsigned)tmp[7] << 16);
        *(uint4*)(&Vtb[(size_t)dr * Sn + sc * 8]) = u;
    }
}

// ===========================================================================
// Pipelined 128x128 GEMM core (verified R3/R4):
// T2 both-sides XOR swizzle, T4 counted vmcnt(4), T5 setprio, T1 XCD chunks.
// ===========================================================================

// ---------------------------------------------------------------------------
// Kernel 1: scores -> S16 (bf16). Triangular grid, XCD-chunked.
// ---------------------------------------------------------------------------
__global__ __launch_bounds__(256) void qk_scores_kernel(
    const unsigned short* __restrict__ Q16, const unsigned short* __restrict__ K16,
    unsigned short* __restrict__ S16) {
    // T1: physical dispatch index -> logical work id, 8 chunks of 68
    const int orig = blockIdx.y * 136 + blockIdx.x;        // 0..543
    const int logical = (orig & 7) * 68 + (orig >> 3);     // bijective (544%8==0)
    const int b = logical / 136;
    const int wid = logical % 136;                          // triangular index
    int qt = (int)((sqrtf(8.0f * wid + 1.0f) - 1.0f) * 0.5f);
    while (qt * (qt + 1) / 2 > wid) qt--;
    while ((qt + 1) * (qt + 2) / 2 <= wid) qt++;
    const int kt = wid - qt * (qt + 1) / 2;
    __shared__ unsigned short As[2][128 * 64];
    __shared__ unsigned short Bs[2][128 * 64];
    const unsigned short* Ag = Q16 + ((size_t)b * Sn + (size_t)qt * 128) * Dn;
    const unsigned short* Bg = K16 + ((size_t)b * Sn + (size_t)kt * 128) * Dn;
    const int t = threadIdx.x;
    const int w = t >> 6, lane = t & 63;
    const int wm = w >> 1, wn = w & 1;
    const int ml = lane & 15, quad = lane >> 4;
    const int srow = lane >> 3, sslot = lane & 7;
    f32x4 acc[4][4] = {};
    const int NT = Dn / 64;  // 16

    auto stageA = [&](int pb, int d0) {
#pragma unroll
        for (int j = 0; j < 4; j++) {
            int row = w * 32 + j * 8 + srow;
            int scol = (sslot ^ (row & 7)) * 8;
            gl_lds16(Ag + (size_t)row * Dn + d0 + scol, &As[pb][(w * 32 + j * 8) * 64]);
        }
    };
    auto stageB = [&](int pb, int d0) {
#pragma unroll
        for (int j = 0; j < 4; j++) {
            int row = w * 32 + j * 8 + srow;
            int scol = (sslot ^ (row & 7)) * 8;
            gl_lds16(Bg + (size_t)row * Dn + d0 + scol, &Bs[pb][(w * 32 + j * 8) * 64]);
        }
    };

    stageA(0, 0);
    stageB(0, 0);
    stageB(1, 64);
    int pb = 0;
    for (int tau = 0; tau < NT; ++tau) {
        if (tau == NT - 1) {
            asm volatile("s_waitcnt vmcnt(0)" ::: "memory");
        } else {
            asm volatile("s_waitcnt vmcnt(4)" ::: "memory");
        }
        __builtin_amdgcn_s_barrier();
        asm volatile("" ::: "memory");
        if (tau + 1 < NT) stageA(pb ^ 1, (tau + 1) * 64);
        // phase 0: all B-frags + A mrep 0
        bf16x8 bfr[4][2];
#pragma unroll
        for (int in = 0; in < 4; in++)
#pragma unroll
            for (int ko = 0; ko < 2; ko++) {
                int r = wn * 64 + in * 16 + ml;
                bfr[in][ko] = *(const bf16x8*)(&Bs[pb][r * 64 + ((ko * 4 + quad) ^ (r & 7)) * 8]);
            }
        {
            int r0 = wm * 64 + ml;
            bf16x8 a0 = *(const bf16x8*)(&As[pb][r0 * 64 + ((quad) ^ (r0 & 7)) * 8]);
            bf16x8 a1 = *(const bf16x8*)(&As[pb][r0 * 64 + ((4 + quad) ^ (r0 & 7)) * 8]);
            __builtin_amdgcn_s_setprio(1);
#pragma unroll
            for (int in = 0; in < 4; in++)
                acc[0][in] = __builtin_amdgcn_mfma_f32_16x16x32_bf16(a0, bfr[in][0], acc[0][in], 0, 0, 0);
#pragma unroll
            for (int in = 0; in < 4; in++)
                acc[0][in] = __builtin_amdgcn_mfma_f32_16x16x32_bf16(a1, bfr[in][1], acc[0][in], 0, 0, 0);
            __builtin_amdgcn_s_setprio(0);
        }
        asm volatile("" ::: "memory");
        __builtin_amdgcn_s_barrier();
        asm volatile("" ::: "memory");
        if (tau + 2 < NT) stageB(pb, (tau + 2) * 64);
        // phases 1..3: A mrep 1..3
#pragma unroll
        for (int im = 1; im < 4; im++) {
            int r0 = wm * 64 + im * 16 + ml;
            bf16x8 a0 = *(const bf16x8*)(&As[pb][r0 * 64 + ((quad) ^ (r0 & 7)) * 8]);
            bf16x8 a1 = *(const bf16x8*)(&As[pb][r0 * 64 + ((4 + quad) ^ (r0 & 7)) * 8]);
            __builtin_amdgcn_s_setprio(1);
#pragma unroll
            for (int in = 0; in < 4; in++)
                acc[im][in] = __builtin_amdgcn_mfma_f32_16x16x32_bf16(a0, bfr[in][0], acc[im][in], 0, 0, 0);
#pragma unroll
            for (int in = 0; in < 4; in++)
                acc[im][in] = __builtin_amdgcn_mfma_f32_16x16x32_bf16(a1, bfr[in][1], acc[im][in], 0, 0, 0);
            __builtin_amdgcn_s_setprio(0);
        }
        pb ^= 1;
    }
    unsigned short* outp = S16 + (size_t)b * Sn * Sn + ((size_t)qt * 128) * Sn + kt * 128;
#pragma unroll
    for (int im = 0; im < 4; im++)
#pragma unroll
        for (int in = 0; in < 4; in++)
#pragma unroll
            for (int r = 0; r < 4; r++) {
                int q = wm * 64 + im * 16 + quad * 4 + r;
                int k = wn * 64 + in * 16 + ml;
                outp[(size_t)q * Sn + k] = (unsigned short)f2bf(acc[im][in][r] * 0.03125f);
            }
}

// ---------------------------------------------------------------------------
// Kernel 2: row softmax over bf16 scores (k<=q). Register-resident,
// fully vectorized. attn is write-only for the rest of the pipeline ->
// nontemporal stores (keep L2/L3 for SP16/Vt). Store via ext-vector f32x4
// (the builtin rejects HIP_vector_type).
// ---------------------------------------------------------------------------
__global__ __launch_bounds__(256) void softmax_kernel(
    unsigned short* __restrict__ SP16, float* __restrict__ attn) {
    const int row = blockIdx.x;
    const int b = row >> 11, q = row & 2047;
    unsigned short* sp = SP16 + (size_t)b * Sn * Sn + (size_t)q * Sn;
    float* ap = attn + (size_t)b * Sn * Sn + (size_t)q * Sn;
    __shared__ float redA[4];
    __shared__ float redB[4];
    const int t = threadIdx.x;
    const int w = t >> 6, lane = t & 63;
    const int nv = q + 1;                       // valid row length
    const int nkr = ((q >> 7) + 1) * 128;       // P16 columns pv will read
    const int base = t * 8;

    float v[8];
    if (base < nv) {
        uint4 u = *(const uint4*)(sp + base);
        v[0] = bf2f((unsigned short)(u.x & 0xFFFF));
        v[1] = bf2f((unsigned short)(u.x >> 16));
        v[2] = bf2f((unsigned short)(u.y & 0xFFFF));
        v[3] = bf2f((unsigned short)(u.y >> 16));
        v[4] = bf2f((unsigned short)(u.z & 0xFFFF));
        v[5] = bf2f((unsigned short)(u.z >> 16));
        v[6] = bf2f((unsigned short)(u.w & 0xFFFF));
        v[7] = bf2f((unsigned short)(u.w >> 16));
#pragma unroll
        for (int j = 0; j < 8; j++)
            if (base + j >= nv) v[j] = -3.0e38f;
    } else {
#pragma unroll
        for (int j = 0; j < 8; j++) v[j] = -3.0e38f;
    }

    float lmax = fmaxf(fmaxf(fmaxf(v[0], v[1]), fmaxf(v[2], v[3])),
                       fmaxf(fmaxf(v[4], v[5]), fmaxf(v[6], v[7])));
#pragma unroll
    for (int o = 32; o > 0; o >>= 1) lmax = fmaxf(lmax, __shfl_xor(lmax, o, 64));
    if (lane == 0) redA[w] = lmax;
    __syncthreads();
    const float m = fmaxf(fmaxf(redA[0], redA[1]), fmaxf(redA[2], redA[3]));

    float lsum = 0.f;
#pragma unroll
    for (int j = 0; j < 8; j++) {
        float e = __expf(v[j] - m);   // masked slots: exp(-huge) == 0
        v[j] = e;
        lsum += e;
    }
#pragma unroll
    for (int o = 32; o > 0; o >>= 1) lsum += __shfl_xor(lsum, o, 64);
    if (lane == 0) redB[w] = lsum;
    __syncthreads();
    const float inv = 1.0f / (redB[0] + redB[1] + redB[2] + redB[3]);

    float r[8];
#pragma unroll
    for (int j = 0; j < 8; j++) r[j] = v[j] * inv;

    f32x4 o0 = {r[0], r[1], r[2], r[3]};
    f32x4 o1 = {r[4], r[5], r[6], r[7]};
    __builtin_nontemporal_store(o0, (f32x4*)(ap + base));
    __builtin_nontemporal_store(o1, (f32x4*)(ap + base + 4));

    if (base < nkr) {
        uint4 u;
        u.x = f2bf(r[0]) | (f2bf(r[1]) << 16);
        u.y = f2bf(r[2]) | (f2bf(r[3]) << 16);
        u.z = f2bf(r[4]) | (f2bf(r[5]) << 16);
        u.w = f2bf(r[6]) | (f2bf(r[7]) << 16);
        *(uint4*)(sp + base) = u;   // re-read by pv: keep cached
    }
}

// ---------------------------------------------------------------------------
// Kernel 3: out = P @ V.
// Perfect CU balance: grid 512 = 2 blocks/CU fully co-resident, so runtime =
// max per-CU work. Map: xcd = p&7; first-round blocks (p<256) get qt=15-xcd,
// second-round (p>=256) qt=xcd -> every CU's pair does (16-x)+(x+1)=17
// k-tile units (ideal). A-panels of an XCD (~2.2 MB) fit its private L2.
// ---------------------------------------------------------------------------
__global__ __launch_bounds__(256) void pv_kernel(
    const unsigned short* __restrict__ P16, const unsigned short* __restrict__ Vt,
    float* __restrict__ out) {
    const int p = blockIdx.x;            // physical 0..511
    const int xcd = p & 7;
    const int s = p >> 3;                // 0..63
    const int half = s >> 5;             // 0 = heavy round, 1 = light round
    const int r5 = s & 31;
    const int b = r5 >> 3;               // 0..3
    const int nt = r5 & 7;               // 0..7
    const int qt = half ? xcd : 15 - xcd;
    __shared__ unsigned short As[2][128 * 64];
    __shared__ unsigned short Bs[2][128 * 64];
    const unsigned short* Ag = P16 + ((size_t)b * Sn + (size_t)qt * 128) * Sn;
    const unsigned short* Bg = Vt + ((size_t)b * Dn + (size_t)nt * 128) * Sn;
    const int t = threadIdx.x;
    const int w = t >> 6, lane = t & 63;
    const int wm = w >> 1, wn = w & 1;
    const int ml = lane & 15, quad = lane >> 4;
    const int srow = lane >> 3, sslot = lane & 7;
    f32x4 acc[4][4] = {};
    const int NT = (qt + 1) * 2;  // k-tiles of 64

    auto stageA = [&](int pb, int k0) {
#pragma unroll
        for (int j = 0; j < 4; j++) {
            int row = w * 32 + j * 8 + srow;
            int scol = (sslot ^ (row & 7)) * 8;
            gl_lds16(Ag + (size_t)row * Sn + k0 + scol, &As[pb][(w * 32 + j * 8) * 64]);
        }
    };
    auto stageB = [&](int pb, int k0) {
#pragma unroll
        for (int j = 0; j < 4; j++) {
            int row = w * 32 + j * 8 + srow;
            int scol = (sslot ^ (row & 7)) * 8;
            gl_lds16(Bg + (size_t)row * Sn + k0 + scol, &Bs[pb][(w * 32 + j * 8) * 64]);
        }
    };

    stageA(0, 0);
    stageB(0, 0);
    stageB(1, 64);
    int pb = 0;
    for (int tau = 0; tau < NT; ++tau) {
        if (tau == NT - 1) {
            asm volatile("s_waitcnt vmcnt(0)" ::: "memory");
        } else {
            asm volatile("s_waitcnt vmcnt(4)" ::: "memory");
        }
        __builtin_amdgcn_s_barrier();
        asm volatile("" ::: "memory");
        if (tau + 1 < NT) stageA(pb ^ 1, (tau + 1) * 64);
        bf16x8 bfr[4][2];
#pragma unroll
        for (int in = 0; in < 4; in++)
#pragma unroll
            for (int ko = 0; ko < 2; ko++) {
                int r = wn * 64 + in * 16 + ml;
                bfr[in][ko] = *(const bf16x8*)(&Bs[pb][r * 64 + ((ko * 4 + quad) ^ (r & 7)) * 8]);
            }
        {
            int r0 = wm * 64 + ml;
            bf16x8 a0 = *(const bf16x8*)(&As[pb][r0 * 64 + ((quad) ^ (r0 & 7)) * 8]);
            bf16x8 a1 = *(const bf16x8*)(&As[pb][r0 * 64 + ((4 + quad) ^ (r0 & 7)) * 8]);
            __builtin_amdgcn_s_setprio(1);
#pragma unroll
            for (int in = 0; in < 4; in++)
                acc[0][in] = __builtin_amdgcn_mfma_f32_16x16x32_bf16(a0, bfr[in][0], acc[0][in], 0, 0, 0);
#pragma unroll
            for (int in = 0; in < 4; in++)
                acc[0][in] = __builtin_amdgcn_mfma_f32_16x16x32_bf16(a1, bfr[in][1], acc[0][in], 0, 0, 0);
            __builtin_amdgcn_s_setprio(0);
        }
        asm volatile("" ::: "memory");
        __builtin_amdgcn_s_barrier();
        asm volatile("" ::: "memory");
        if (tau + 2 < NT) stageB(pb, (tau + 2) * 64);
#pragma unroll
        for (int im = 1; im < 4; im++) {
            int r0 = wm * 64 + im * 16 + ml;
            bf16x8 a0 = *(const bf16x8*)(&As[pb][r0 * 64 + ((quad) ^ (r0 & 7)) * 8]);
            bf16x8 a1 = *(const bf16x8*)(&As[pb][r0 * 64 + ((4 + quad) ^ (r0 & 7)) * 8]);
            __builtin_amdgcn_s_setprio(1);
#pragma unroll
            for (int in = 0; in < 4; in++)
                acc[im][in] = __builtin_amdgcn_mfma_f32_16x16x32_bf16(a0, bfr[in][0], acc[im][in], 0, 0, 0);
#pragma unroll
            for (int in = 0; in < 4; in++)
                acc[im][in] = __builtin_amdgcn_mfma_f32_16x16x32_bf16(a1, bfr[in][1], acc[im][in], 0, 0, 0);
            __builtin_amdgcn_s_setprio(0);
        }
        pb ^= 1;
    }
    float* ob = out + (size_t)b * Sn * Dn + ((size_t)qt * 128) * Dn + nt * 128;
#pragma unroll
    for (int im = 0; im < 4; im++)
#pragma unroll
        for (int in = 0; in < 4; in++)
#pragma unroll
            for (int r = 0; r < 4; r++) {
                int q = wm * 64 + im * 16 + quad * 4 + r;
                int n = wn * 64 + in * 16 + ml;
                __builtin_nontemporal_store(acc[im][in][r], &ob[(size_t)q * Dn + n]);
            }
}

extern "C" void kernel_launch(void* const* d_in, const int* in_sizes, int n_in,
                              void* d_out, int out_size, void* d_ws, size_t ws_size,
                              hipStream_t stream) {
    const float* Q = (const float*)d_in[0];
    const float* K = (const float*)d_in[1];
    const float* V = (const float*)d_in[2];
    float* out = (float*)d_out;
    float* attn = out + (size_t)Bn * Sn * Dn;

    // workspace (bf16): Q16 16MB | K16 16MB | Vt 16MB | SP16 32MB = 80MB
    unsigned short* Q16 = (unsigned short*)d_ws;
    unsigned short* K16 = Q16 + (size_t)Bn * Sn * Dn;
    unsigned short* Vt  = K16 + (size_t)Bn * Sn * Dn;
    unsigned short* SP16 = Vt + (size_t)Bn * Dn * Sn;

    prep_kernel<<<dim3(8192 + 1024), 256, 0, stream>>>(Q, K, V, Q16, K16, Vt);

    qk_scores_kernel<<<dim3(136, Bn), 256, 0, stream>>>(Q16, K16, SP16);
    softmax_kernel<<<dim3(Bn * Sn), 256, 0, stream>>>(SP16, attn);
    pv_kernel<<<dim3(512), 256, 0, stream>>>(SP16, Vt, out);
}

// Round 7
// 276.275 us; speedup vs baseline: 1.0629x; 1.0629x over previous
//
#include <hip/hip_runtime.h>

#define Bn 4
#define Sn 2048
#define Dn 1024

typedef short bf16x8 __attribute__((ext_vector_type(8)));
typedef float f32x4 __attribute__((ext_vector_type(4)));

__device__ __forceinline__ unsigned f2bf(float x) {
    unsigned u = __float_as_uint(x);
    return (u + 0x7FFFu + ((u >> 16) & 1u)) >> 16;
}

__device__ __forceinline__ uint2 pack4(float4 v) {
    uint2 p;
    p.x = f2bf(v.x) | (f2bf(v.y) << 16);
    p.y = f2bf(v.z) | (f2bf(v.w) << 16);
    return p;
}

__device__ __forceinline__ float bf2f(unsigned short s) {
    return __uint_as_float((unsigned)s << 16);
}

__device__ __forceinline__ void gl_lds16(const unsigned short* g, unsigned short* l) {
    __builtin_amdgcn_global_load_lds(
        (const __attribute__((address_space(1))) unsigned int*)g,
        (__attribute__((address_space(3))) unsigned int*)l, 16, 0, 0);
}

// ---------------------------------------------------------------------------
// Prep (fused): blocks [0,8192) copy-convert Q,K fp32->bf16;
// blocks [8192,9216) transpose V fp32 [B][S][D] -> Vt bf16 [B][D][S].
// ---------------------------------------------------------------------------
__global__ __launch_bounds__(256) void prep_kernel(
    const float* __restrict__ Q, const float* __restrict__ K,
    const float* __restrict__ V,
    unsigned short* __restrict__ Q16, unsigned short* __restrict__ K16,
    unsigned short* __restrict__ Vt) {
    __shared__ unsigned short Ts[128 * 66];
    const int bid = blockIdx.x;
    const int t = threadIdx.x;
    if (bid < 8192) {
        size_t i = (size_t)bid * 256 + t;
        float4 q = ((const float4*)Q)[i];
        ((uint2*)Q16)[i] = pack4(q);
        float4 k = ((const float4*)K)[i];
        ((uint2*)K16)[i] = pack4(k);
        return;
    }
    const int tb = bid - 8192;  // 1024 transpose tiles
    const int s0 = (tb & 15) * 128, d0 = ((tb >> 4) & 15) * 64, b = tb >> 8;
    const float* Vb = V + ((size_t)b * Sn + s0) * Dn + d0;
#pragma unroll
    for (int i = 0; i < 8; i++) {
        int task = i * 256 + t;
        int r = task >> 4, c4 = task & 15;
        float4 v = *(const float4*)(Vb + (size_t)r * Dn + c4 * 4);
        *(uint2*)(&Ts[r * 66 + c4 * 4]) = pack4(v);
    }
    __syncthreads();
    unsigned short* Vtb = Vt + ((size_t)b * Dn + d0) * Sn + s0;
#pragma unroll
    for (int i = 0; i < 4; i++) {
        int task = i * 256 + t;
        int sc = task & 15, dr = task >> 4;
        unsigned short tmp[8];
#pragma unroll
        for (int j = 0; j < 8; j++) tmp[j] = Ts[(sc * 8 + j) * 66 + dr];
        uint4 u;
        u.x = tmp[0] | ((unsigned)tmp[1] << 16);
        u.y = tmp[2] | ((unsigned)tmp[3] << 16);
        u.z = tmp[4] | ((unsigned)tmp[5] << 16);
        u.w = tmp[6] | ((unsigned)tmp[7] << 16);
        *(uint4*)(&Vtb[(size_t)dr * Sn + sc * 8]) = u;
    }
}

// ===========================================================================
// Pipelined 128x128 GEMM core (verified R3/R4):
// T2 both-sides XOR swizzle, T4 counted vmcnt(4), T5 setprio, T1 XCD chunks.
// ===========================================================================

// ---------------------------------------------------------------------------
// Kernel 1: scores -> S16 (bf16). Triangular grid, XCD-chunked.
// ---------------------------------------------------------------------------
__global__ __launch_bounds__(256) void qk_scores_kernel(
    const unsigned short* __restrict__ Q16, const unsigned short* __restrict__ K16,
    unsigned short* __restrict__ S16) {
    // T1: physical dispatch index -> logical work id, 8 chunks of 68
    const int orig = blockIdx.y * 136 + blockIdx.x;        // 0..543
    const int logical = (orig & 7) * 68 + (orig >> 3);     // bijective (544%8==0)
    const int b = logical / 136;
    const int wid = logical % 136;                          // triangular index
    int qt = (int)((sqrtf(8.0f * wid + 1.0f) - 1.0f) * 0.5f);
    while (qt * (qt + 1) / 2 > wid) qt--;
    while ((qt + 1) * (qt + 2) / 2 <= wid) qt++;
    const int kt = wid - qt * (qt + 1) / 2;
    __shared__ unsigned short As[2][128 * 64];
    __shared__ unsigned short Bs[2][128 * 64];
    const unsigned short* Ag = Q16 + ((size_t)b * Sn + (size_t)qt * 128) * Dn;
    const unsigned short* Bg = K16 + ((size_t)b * Sn + (size_t)kt * 128) * Dn;
    const int t = threadIdx.x;
    const int w = t >> 6, lane = t & 63;
    const int wm = w >> 1, wn = w & 1;
    const int ml = lane & 15, quad = lane >> 4;
    const int srow = lane >> 3, sslot = lane & 7;
    f32x4 acc[4][4] = {};
    const int NT = Dn / 64;  // 16

    auto stageA = [&](int pb, int d0) {
#pragma unroll
        for (int j = 0; j < 4; j++) {
            int row = w * 32 + j * 8 + srow;
            int scol = (sslot ^ (row & 7)) * 8;
            gl_lds16(Ag + (size_t)row * Dn + d0 + scol, &As[pb][(w * 32 + j * 8) * 64]);
        }
    };
    auto stageB = [&](int pb, int d0) {
#pragma unroll
        for (int j = 0; j < 4; j++) {
            int row = w * 32 + j * 8 + srow;
            int scol = (sslot ^ (row & 7)) * 8;
            gl_lds16(Bg + (size_t)row * Dn + d0 + scol, &Bs[pb][(w * 32 + j * 8) * 64]);
        }
    };

    stageA(0, 0);
    stageB(0, 0);
    stageB(1, 64);
    int pb = 0;
    for (int tau = 0; tau < NT; ++tau) {
        if (tau == NT - 1) {
            asm volatile("s_waitcnt vmcnt(0)" ::: "memory");
        } else {
            asm volatile("s_waitcnt vmcnt(4)" ::: "memory");
        }
        __builtin_amdgcn_s_barrier();
        asm volatile("" ::: "memory");
        if (tau + 1 < NT) stageA(pb ^ 1, (tau + 1) * 64);
        // phase 0: all B-frags + A mrep 0
        bf16x8 bfr[4][2];
#pragma unroll
        for (int in = 0; in < 4; in++)
#pragma unroll
            for (int ko = 0; ko < 2; ko++) {
                int r = wn * 64 + in * 16 + ml;
                bfr[in][ko] = *(const bf16x8*)(&Bs[pb][r * 64 + ((ko * 4 + quad) ^ (r & 7)) * 8]);
            }
        {
            int r0 = wm * 64 + ml;
            bf16x8 a0 = *(const bf16x8*)(&As[pb][r0 * 64 + ((quad) ^ (r0 & 7)) * 8]);
            bf16x8 a1 = *(const bf16x8*)(&As[pb][r0 * 64 + ((4 + quad) ^ (r0 & 7)) * 8]);
            __builtin_amdgcn_s_setprio(1);
#pragma unroll
            for (int in = 0; in < 4; in++)
                acc[0][in] = __builtin_amdgcn_mfma_f32_16x16x32_bf16(a0, bfr[in][0], acc[0][in], 0, 0, 0);
#pragma unroll
            for (int in = 0; in < 4; in++)
                acc[0][in] = __builtin_amdgcn_mfma_f32_16x16x32_bf16(a1, bfr[in][1], acc[0][in], 0, 0, 0);
            __builtin_amdgcn_s_setprio(0);
        }
        asm volatile("" ::: "memory");
        __builtin_amdgcn_s_barrier();
        asm volatile("" ::: "memory");
        if (tau + 2 < NT) stageB(pb, (tau + 2) * 64);
        // phases 1..3: A mrep 1..3
#pragma unroll
        for (int im = 1; im < 4; im++) {
            int r0 = wm * 64 + im * 16 + ml;
            bf16x8 a0 = *(const bf16x8*)(&As[pb][r0 * 64 + ((quad) ^ (r0 & 7)) * 8]);
            bf16x8 a1 = *(const bf16x8*)(&As[pb][r0 * 64 + ((4 + quad) ^ (r0 & 7)) * 8]);
            __builtin_amdgcn_s_setprio(1);
#pragma unroll
            for (int in = 0; in < 4; in++)
                acc[im][in] = __builtin_amdgcn_mfma_f32_16x16x32_bf16(a0, bfr[in][0], acc[im][in], 0, 0, 0);
#pragma unroll
            for (int in = 0; in < 4; in++)
                acc[im][in] = __builtin_amdgcn_mfma_f32_16x16x32_bf16(a1, bfr[in][1], acc[im][in], 0, 0, 0);
            __builtin_amdgcn_s_setprio(0);
        }
        pb ^= 1;
    }
    unsigned short* outp = S16 + (size_t)b * Sn * Sn + ((size_t)qt * 128) * Sn + kt * 128;
#pragma unroll
    for (int im = 0; im < 4; im++)
#pragma unroll
        for (int in = 0; in < 4; in++)
#pragma unroll
            for (int r = 0; r < 4; r++) {
                int q = wm * 64 + im * 16 + quad * 4 + r;
                int k = wn * 64 + in * 16 + ml;
                outp[(size_t)q * Sn + k] = (unsigned short)f2bf(acc[im][in][r] * 0.03125f);
            }
}

// ---------------------------------------------------------------------------
// Kernel 2: row softmax over bf16 scores (k<=q). Register-resident,
// fully vectorized: thread t owns elems [8t, 8t+8) of its row.
// ---------------------------------------------------------------------------
__global__ __launch_bounds__(256) void softmax_kernel(
    unsigned short* __restrict__ SP16, float* __restrict__ attn) {
    const int row = blockIdx.x;
    const int b = row >> 11, q = row & 2047;
    unsigned short* sp = SP16 + (size_t)b * Sn * Sn + (size_t)q * Sn;
    float* ap = attn + (size_t)b * Sn * Sn + (size_t)q * Sn;
    __shared__ float redA[4];
    __shared__ float redB[4];
    const int t = threadIdx.x;
    const int w = t >> 6, lane = t & 63;
    const int nv = q + 1;                       // valid row length
    const int nkr = ((q >> 7) + 1) * 128;       // P16 columns pv will read
    const int base = t * 8;

    float v[8];
    if (base < nv) {
        uint4 u = *(const uint4*)(sp + base);
        v[0] = bf2f((unsigned short)(u.x & 0xFFFF));
        v[1] = bf2f((unsigned short)(u.x >> 16));
        v[2] = bf2f((unsigned short)(u.y & 0xFFFF));
        v[3] = bf2f((unsigned short)(u.y >> 16));
        v[4] = bf2f((unsigned short)(u.z & 0xFFFF));
        v[5] = bf2f((unsigned short)(u.z >> 16));
        v[6] = bf2f((unsigned short)(u.w & 0xFFFF));
        v[7] = bf2f((unsigned short)(u.w >> 16));
#pragma unroll
        for (int j = 0; j < 8; j++)
            if (base + j >= nv) v[j] = -3.0e38f;
    } else {
#pragma unroll
        for (int j = 0; j < 8; j++) v[j] = -3.0e38f;
    }

    float lmax = fmaxf(fmaxf(fmaxf(v[0], v[1]), fmaxf(v[2], v[3])),
                       fmaxf(fmaxf(v[4], v[5]), fmaxf(v[6], v[7])));
#pragma unroll
    for (int o = 32; o > 0; o >>= 1) lmax = fmaxf(lmax, __shfl_xor(lmax, o, 64));
    if (lane == 0) redA[w] = lmax;
    __syncthreads();
    const float m = fmaxf(fmaxf(redA[0], redA[1]), fmaxf(redA[2], redA[3]));

    float lsum = 0.f;
#pragma unroll
    for (int j = 0; j < 8; j++) {
        float e = __expf(v[j] - m);   // masked slots: exp(-huge) == 0
        v[j] = e;
        lsum += e;
    }
#pragma unroll
    for (int o = 32; o > 0; o >>= 1) lsum += __shfl_xor(lsum, o, 64);
    if (lane == 0) redB[w] = lsum;
    __syncthreads();
    const float inv = 1.0f / (redB[0] + redB[1] + redB[2] + redB[3]);

    float r[8];
#pragma unroll
    for (int j = 0; j < 8; j++) r[j] = v[j] * inv;

    float4 o0 = {r[0], r[1], r[2], r[3]};
    float4 o1 = {r[4], r[5], r[6], r[7]};
    *(float4*)(ap + base) = o0;
    *(float4*)(ap + base + 4) = o1;

    if (base < nkr) {
        uint4 u;
        u.x = f2bf(r[0]) | (f2bf(r[1]) << 16);
        u.y = f2bf(r[2]) | (f2bf(r[3]) << 16);
        u.z = f2bf(r[4]) | (f2bf(r[5]) << 16);
        u.w = f2bf(r[6]) | (f2bf(r[7]) << 16);
        *(uint4*)(sp + base) = u;
    }
}

// ---------------------------------------------------------------------------
// Kernel 3: out = P @ V. XCD-chunked swizzle; consecutive nt share the
// A-panel (8x L2 reuse within a chunk). qt descending: heavy first.
// ---------------------------------------------------------------------------
__global__ __launch_bounds__(256) void pv_kernel(
    const unsigned short* __restrict__ P16, const unsigned short* __restrict__ Vt,
    float* __restrict__ out) {
    const int orig = blockIdx.x;                       // 0..511
    const int id = (orig & 7) * 64 + (orig >> 3);      // T1 bijective (512%8==0)
    const int qt = 15 - (id >> 5);                     // heavy first per chunk
    const int rest = id & 31;
    const int nt = rest & 7, b = rest >> 3;
    __shared__ unsigned short As[2][128 * 64];
    __shared__ unsigned short Bs[2][128 * 64];
    const unsigned short* Ag = P16 + ((size_t)b * Sn + (size_t)qt * 128) * Sn;
    const unsigned short* Bg = Vt + ((size_t)b * Dn + (size_t)nt * 128) * Sn;
    const int t = threadIdx.x;
    const int w = t >> 6, lane = t & 63;
    const int wm = w >> 1, wn = w & 1;
    const int ml = lane & 15, quad = lane >> 4;
    const int srow = lane >> 3, sslot = lane & 7;
    f32x4 acc[4][4] = {};
    const int NT = (qt + 1) * 2;  // k-tiles of 64

    auto stageA = [&](int pb, int k0) {
#pragma unroll
        for (int j = 0; j < 4; j++) {
            int row = w * 32 + j * 8 + srow;
            int scol = (sslot ^ (row & 7)) * 8;
            gl_lds16(Ag + (size_t)row * Sn + k0 + scol, &As[pb][(w * 32 + j * 8) * 64]);
        }
    };
    auto stageB = [&](int pb, int k0) {
#pragma unroll
        for (int j = 0; j < 4; j++) {
            int row = w * 32 + j * 8 + srow;
            int scol = (sslot ^ (row & 7)) * 8;
            gl_lds16(Bg + (size_t)row * Sn + k0 + scol, &Bs[pb][(w * 32 + j * 8) * 64]);
        }
    };

    stageA(0, 0);
    stageB(0, 0);
    stageB(1, 64);
    int pb = 0;
    for (int tau = 0; tau < NT; ++tau) {
        if (tau == NT - 1) {
            asm volatile("s_waitcnt vmcnt(0)" ::: "memory");
        } else {
            asm volatile("s_waitcnt vmcnt(4)" ::: "memory");
        }
        __builtin_amdgcn_s_barrier();
        asm volatile("" ::: "memory");
        if (tau + 1 < NT) stageA(pb ^ 1, (tau + 1) * 64);
        bf16x8 bfr[4][2];
#pragma unroll
        for (int in = 0; in < 4; in++)
#pragma unroll
            for (int ko = 0; ko < 2; ko++) {
                int r = wn * 64 + in * 16 + ml;
                bfr[in][ko] = *(const bf16x8*)(&Bs[pb][r * 64 + ((ko * 4 + quad) ^ (r & 7)) * 8]);
            }
        {
            int r0 = wm * 64 + ml;
            bf16x8 a0 = *(const bf16x8*)(&As[pb][r0 * 64 + ((quad) ^ (r0 & 7)) * 8]);
            bf16x8 a1 = *(const bf16x8*)(&As[pb][r0 * 64 + ((4 + quad) ^ (r0 & 7)) * 8]);
            __builtin_amdgcn_s_setprio(1);
#pragma unroll
            for (int in = 0; in < 4; in++)
                acc[0][in] = __builtin_amdgcn_mfma_f32_16x16x32_bf16(a0, bfr[in][0], acc[0][in], 0, 0, 0);
#pragma unroll
            for (int in = 0; in < 4; in++)
                acc[0][in] = __builtin_amdgcn_mfma_f32_16x16x32_bf16(a1, bfr[in][1], acc[0][in], 0, 0, 0);
            __builtin_amdgcn_s_setprio(0);
        }
        asm volatile("" ::: "memory");
        __builtin_amdgcn_s_barrier();
        asm volatile("" ::: "memory");
        if (tau + 2 < NT) stageB(pb, (tau + 2) * 64);
#pragma unroll
        for (int im = 1; im < 4; im++) {
            int r0 = wm * 64 + im * 16 + ml;
            bf16x8 a0 = *(const bf16x8*)(&As[pb][r0 * 64 + ((quad) ^ (r0 & 7)) * 8]);
            bf16x8 a1 = *(const bf16x8*)(&As[pb][r0 * 64 + ((4 + quad) ^ (r0 & 7)) * 8]);
            __builtin_amdgcn_s_setprio(1);
#pragma unroll
            for (int in = 0; in < 4; in++)
                acc[im][in] = __builtin_amdgcn_mfma_f32_16x16x32_bf16(a0, bfr[in][0], acc[im][in], 0, 0, 0);
#pragma unroll
            for (int in = 0; in < 4; in++)
                acc[im][in] = __builtin_amdgcn_mfma_f32_16x16x32_bf16(a1, bfr[in][1], acc[im][in], 0, 0, 0);
            __builtin_amdgcn_s_setprio(0);
        }
        pb ^= 1;
    }
    float* ob = out + (size_t)b * Sn * Dn + ((size_t)qt * 128) * Dn + nt * 128;
#pragma unroll
    for (int im = 0; im < 4; im++)
#pragma unroll
        for (int in = 0; in < 4; in++)
#pragma unroll
            for (int r = 0; r < 4; r++) {
                int q = wm * 64 + im * 16 + quad * 4 + r;
                int n = wn * 64 + in * 16 + ml;
                ob[(size_t)q * Dn + n] = acc[im][in][r];
            }
}

extern "C" void kernel_launch(void* const* d_in, const int* in_sizes, int n_in,
                              void* d_out, int out_size, void* d_ws, size_t ws_size,
                              hipStream_t stream) {
    const float* Q = (const float*)d_in[0];
    const float* K = (const float*)d_in[1];
    const float* V = (const float*)d_in[2];
    float* out = (float*)d_out;
    float* attn = out + (size_t)Bn * Sn * Dn;

    // workspace (bf16): Q16 16MB | K16 16MB | Vt 16MB | SP16 32MB = 80MB
    unsigned short* Q16 = (unsigned short*)d_ws;
    unsigned short* K16 = Q16 + (size_t)Bn * Sn * Dn;
    unsigned short* Vt  = K16 + (size_t)Bn * Sn * Dn;
    unsigned short* SP16 = Vt + (size_t)Bn * Dn * Sn;

    prep_kernel<<<dim3(8192 + 1024), 256, 0, stream>>>(Q, K, V, Q16, K16, Vt);

    qk_scores_kernel<<<dim3(136, Bn), 256, 0, stream>>>(Q16, K16, SP16);
    softmax_kernel<<<dim3(Bn * Sn), 256, 0, stream>>>(SP16, attn);
    pv_kernel<<<dim3(512), 256, 0, stream>>>(SP16, Vt, out);
}